// Round 1
// baseline (366.800 us; speedup 1.0000x reference)
//
#include <hip/hip_runtime.h>

typedef __attribute__((ext_vector_type(8))) short s8v;
typedef __attribute__((ext_vector_type(4))) short s4v;
typedef __attribute__((ext_vector_type(4))) float f4v;

#define LDK 136  // K tile row stride in bf16 elems (128+8): 2-way bank alias on b128 reads
#define LDV 72   // V^T row stride (64+8): 16B-aligned rows, 2-way alias
#define LDP 72   // P row stride (64+8): 16B-aligned rows, 2-way alias

__device__ __forceinline__ unsigned short f2b(float f) {
  unsigned int u = __builtin_bit_cast(unsigned int, f);
  u += 0x7fffu + ((u >> 16) & 1u);  // RNE
  return (unsigned short)(u >> 16);
}
__device__ __forceinline__ float b2f(unsigned short b) {
  unsigned int u = ((unsigned int)b) << 16;
  return __builtin_bit_cast(float, u);
}

__global__ __launch_bounds__(256) void gqa_attn_kernel(
    const float* __restrict__ Q, const float* __restrict__ K,
    const float* __restrict__ V, float* __restrict__ O) {
  constexpr int S = 2048, Dh = 128;
  // scores pre-scaled by 1/sqrt(D) and log2(e) so softmax uses exp2
  constexpr float QS = 0.08838834764831845f * 1.4426950408889634f;

  __shared__ unsigned short kl[64 * LDK];    // K tile, row-major [t][d]
  __shared__ unsigned short vt[128 * LDV];   // V tile transposed [d][t]
  __shared__ unsigned short pl[4 * 16 * LDP];// P per wave, row-major [q][t]

  const int tid = threadIdx.x;
  const int l = tid & 63, w = tid >> 6;
  const int lane15 = l & 15, quad = l >> 4;

  const int bx = blockIdx.x;
  const int bh = bx >> 5;          // b*16 + h
  const int qt = 31 - (bx & 31);   // heavy q-tiles first
  const int b = bh >> 4, h = bh & 15;
  const int hkv = h >> 1;          // GQA group of 2

  const float* Qb = Q + ((size_t)bh * S) * Dh;
  const float* Kb = K + ((size_t)(b * 8 + hkv) * S) * Dh;
  const float* Vb = V + ((size_t)(b * 8 + hkv) * S) * Dh;
  float* Ob = O + ((size_t)bh * S) * Dh;

  // ---- Q fragments (A-layout: A[m=lane15][k=32c+quad*8+j]), loaded once ----
  const int qrow = qt * 64 + w * 16 + lane15;
  const float* qp = Qb + (size_t)qrow * Dh;
  s8v qf[4];
#pragma unroll
  for (int c = 0; c < 4; ++c) {
    const float4 x = *(const float4*)(qp + 32 * c + quad * 8);
    const float4 y = *(const float4*)(qp + 32 * c + quad * 8 + 4);
    qf[c] = (s8v){(short)f2b(x.x * QS), (short)f2b(x.y * QS),
                  (short)f2b(x.z * QS), (short)f2b(x.w * QS),
                  (short)f2b(y.x * QS), (short)f2b(y.y * QS),
                  (short)f2b(y.z * QS), (short)f2b(y.w * QS)};
  }

  f4v o4[8];  // O^T accumulators: o4[mt][r] = O[q=lane15][d=mt*16+quad*4+r]
#pragma unroll
  for (int i = 0; i < 8; ++i) o4[i] = (f4v){0.f, 0.f, 0.f, 0.f};
  float m_i[4] = {-1e30f, -1e30f, -1e30f, -1e30f};
  float l_i[4] = {0.f, 0.f, 0.f, 0.f};

  // staging assignments
  const int kt = tid >> 2, kp4 = tid & 3;     // K: row kt, 32-col block kp4
  const int vtq = tid >> 4, vdq0 = tid & 15;  // V: 4 rows at 4*vtq, d-quad vdq0/+16

  for (int kb = 0; kb <= qt; ++kb) {
    __syncthreads();  // previous tile's LDS reads done before overwrite

    // ---- stage K tile (64x128) fp32 -> bf16, row-major ----
    {
      const float* kr = Kb + ((size_t)(kb * 64 + kt)) * Dh + 32 * kp4;
#pragma unroll
      for (int g = 0; g < 4; ++g) {
        const float4 x = *(const float4*)(kr + 8 * g);
        const float4 y = *(const float4*)(kr + 8 * g + 4);
        s8v kv = (s8v){(short)f2b(x.x), (short)f2b(x.y), (short)f2b(x.z),
                       (short)f2b(x.w), (short)f2b(y.x), (short)f2b(y.y),
                       (short)f2b(y.z), (short)f2b(y.w)};
        *(s8v*)&kl[kt * LDK + 32 * kp4 + 8 * g] = kv;
      }
    }
    // ---- stage V tile transposed: vt[d][t] ----
#pragma unroll
    for (int u = 0; u < 2; ++u) {
      const int dq = vdq0 + 16 * u, d0 = 4 * dq, t0 = 4 * vtq;
      const float* vr = Vb + ((size_t)(kb * 64 + t0)) * Dh + d0;
      const float4 r0 = *(const float4*)(vr);
      const float4 r1 = *(const float4*)(vr + Dh);
      const float4 r2 = *(const float4*)(vr + 2 * Dh);
      const float4 r3 = *(const float4*)(vr + 3 * Dh);
      const float* f0 = (const float*)&r0;
      const float* f1 = (const float*)&r1;
      const float* f2 = (const float*)&r2;
      const float* f3 = (const float*)&r3;
#pragma unroll
      for (int c = 0; c < 4; ++c) {
        s4v pk = (s4v){(short)f2b(f0[c]), (short)f2b(f1[c]),
                       (short)f2b(f2[c]), (short)f2b(f3[c])};
        *(s4v*)&vt[(d0 + c) * LDV + t0] = pk;
      }
    }
    __syncthreads();

    // ---- S = Q K^T  (C-layout: row=query=quad*4+r, col=key=cb*16+lane15) ----
    f4v s4[4];
#pragma unroll
    for (int cb = 0; cb < 4; ++cb) {
      s4[cb] = (f4v){0.f, 0.f, 0.f, 0.f};
#pragma unroll
      for (int c = 0; c < 4; ++c) {
        s8v kf = *(const s8v*)&kl[(cb * 16 + lane15) * LDK + 32 * c + quad * 8];
        s4[cb] = __builtin_amdgcn_mfma_f32_16x16x32_bf16(qf[c], kf, s4[cb], 0, 0, 0);
      }
    }

    // ---- causal mask (diagonal tile only) ----
    if (kb == qt) {
#pragma unroll
      for (int cb = 0; cb < 4; ++cb) {
        const int key = cb * 16 + lane15;
#pragma unroll
        for (int r = 0; r < 4; ++r) {
          const int qq = w * 16 + quad * 4 + r;
          if (key > qq) s4[cb][r] = -1e30f;
        }
      }
    }

    // ---- online softmax (stats per row r of this quad) ----
    float alpha[4];
#pragma unroll
    for (int r = 0; r < 4; ++r) {
      float m0 = fmaxf(fmaxf(s4[0][r], s4[1][r]), fmaxf(s4[2][r], s4[3][r]));
      m0 = fmaxf(m0, __shfl_xor(m0, 1));
      m0 = fmaxf(m0, __shfl_xor(m0, 2));
      m0 = fmaxf(m0, __shfl_xor(m0, 4));
      m0 = fmaxf(m0, __shfl_xor(m0, 8));
      const float mn = fmaxf(m_i[r], m0);
      alpha[r] = __builtin_amdgcn_exp2f(m_i[r] - mn);
      m_i[r] = mn;
      float s = 0.f;
#pragma unroll
      for (int cb = 0; cb < 4; ++cb) {
        const float p = __builtin_amdgcn_exp2f(s4[cb][r] - mn);
        const unsigned short pb = f2b(p);
        pl[w * 16 * LDP + (quad * 4 + r) * LDP + cb * 16 + lane15] = pb;
        s += b2f(pb);  // denominator from the rounded numerator
      }
      s += __shfl_xor(s, 1);
      s += __shfl_xor(s, 2);
      s += __shfl_xor(s, 4);
      s += __shfl_xor(s, 8);
      l_i[r] = l_i[r] * alpha[r] + s;
    }

    // ---- rescale O^T by alpha of this lane's query (= lane15) ----
    {
      const int srcl = (lane15 >> 2) << 4;
      const float a0 = __shfl(alpha[0], srcl);
      const float a1 = __shfl(alpha[1], srcl);
      const float a2 = __shfl(alpha[2], srcl);
      const float a3 = __shfl(alpha[3], srcl);
      const int rr = lane15 & 3;
      const float aq = rr == 0 ? a0 : rr == 1 ? a1 : rr == 2 ? a2 : a3;
#pragma unroll
      for (int mt = 0; mt < 8; ++mt) {
        o4[mt][0] *= aq; o4[mt][1] *= aq; o4[mt][2] *= aq; o4[mt][3] *= aq;
      }
    }

    // ---- O^T += V^T * P^T ----
#pragma unroll
    for (int c = 0; c < 2; ++c) {
      s8v pf = *(const s8v*)&pl[w * 16 * LDP + lane15 * LDP + 32 * c + quad * 8];
#pragma unroll
      for (int mt = 0; mt < 8; ++mt) {
        s8v vf = *(const s8v*)&vt[(mt * 16 + lane15) * LDV + 32 * c + quad * 8];
        o4[mt] = __builtin_amdgcn_mfma_f32_16x16x32_bf16(vf, pf, o4[mt], 0, 0, 0);
      }
    }
  }

  // ---- epilogue: divide by l, store fp32 ----
  {
    const int srcl = (lane15 >> 2) << 4;
    const float l0 = __shfl(l_i[0], srcl);
    const float l1 = __shfl(l_i[1], srcl);
    const float l2 = __shfl(l_i[2], srcl);
    const float l3 = __shfl(l_i[3], srcl);
    const int rr = lane15 & 3;
    const float lq = rr == 0 ? l0 : rr == 1 ? l1 : rr == 2 ? l2 : l3;
    const float inv = 1.0f / lq;
    float* op = Ob + (size_t)(qt * 64 + w * 16 + lane15) * Dh;
#pragma unroll
    for (int mt = 0; mt < 8; ++mt) {
      float4 st;
      st.x = o4[mt][0] * inv;
      st.y = o4[mt][1] * inv;
      st.z = o4[mt][2] * inv;
      st.w = o4[mt][3] * inv;
      *(float4*)(op + mt * 16 + quad * 4) = st;
    }
  }
}

extern "C" void kernel_launch(void* const* d_in, const int* in_sizes, int n_in,
                              void* d_out, int out_size, void* d_ws, size_t ws_size,
                              hipStream_t stream) {
  const float* q = (const float*)d_in[0];
  const float* k = (const float*)d_in[1];
  const float* v = (const float*)d_in[2];
  float* o = (float*)d_out;
  // grid: 32 (b,h) pairs x 32 q-tiles of 64 rows
  gqa_attn_kernel<<<dim3(1024), dim3(256), 0, stream>>>(q, k, v, o);
}

// Round 2
// 199.480 us; speedup vs baseline: 1.8388x; 1.8388x over previous
//
#include <hip/hip_runtime.h>

typedef __attribute__((ext_vector_type(8))) short s8v;
typedef __attribute__((ext_vector_type(4))) short s4v;
typedef __attribute__((ext_vector_type(16))) float f16vf;

#define LDK 136  // K tile row stride (128+8 bf16): bank-spread for b128 reads
#define LDV 72   // V^T row stride (64+8)
#define LDP 72   // P^T row stride (64+8)

static __device__ __forceinline__ unsigned short f2b(float f) {
  unsigned int u = __builtin_bit_cast(unsigned int, f);
  u += 0x7fffu + ((u >> 16) & 1u);  // RNE
  return (unsigned short)(u >> 16);
}
static __device__ __forceinline__ float b2f(unsigned short b) {
  unsigned int u = ((unsigned int)b) << 16;
  return __builtin_bit_cast(float, u);
}

__global__ __launch_bounds__(256, 2) void gqa_attn_kernel(
    const float* __restrict__ Q, const float* __restrict__ K,
    const float* __restrict__ V, float* __restrict__ O) {
  constexpr int S = 2048, Dh = 128;
  constexpr float QS = 0.08838834764831845f * 1.4426950408889634f;  // 1/sqrt(128)*log2(e)

  __shared__ unsigned short kl[64 * LDK];    // K tile row-major [t][d]
  __shared__ unsigned short vt[128 * LDV];   // V tile transposed [d][t]
  __shared__ unsigned short pl[4 * 32 * LDP];// P^T per wave, [q][t]

  const int tid = threadIdx.x;
  const int l = tid & 63, w = tid >> 6;
  const int col = l & 31, hh = l >> 5;  // 32x32 MFMA: col = n/m index, hh = k-half

  const int bx = blockIdx.x;
  const int bh = bx & 31;              // b*16 + h
  const int g = bx >> 5;               // 0..15
  // zigzag: blocks bx and bx+256 (same CU under round-robin dispatch) get
  // qt and 15-qt -> constant combined work (34 tile-iters); heavy first.
  const int qt = (g < 8) ? (15 - g) : (g - 8);
  const int b = bh >> 4, h = bh & 15;
  const int hkv = h >> 1;

  const float* Qb = Q + ((size_t)bh * S) * Dh;
  const float* Kb = K + ((size_t)(b * 8 + hkv) * S) * Dh;
  const float* Vb = V + ((size_t)(b * 8 + hkv) * S) * Dh;
  float* Ob = O + ((size_t)bh * S) * Dh;

  // ---- Q fragments (B-layout for S^T=K*Q^T): lane holds Q[q=col][d=16ks+8hh+j]
  const int qrow = qt * 128 + w * 32 + col;
  const float* qp = Qb + (size_t)qrow * Dh;
  s8v qf[8];
#pragma unroll
  for (int ks = 0; ks < 8; ++ks) {
    const float4 x = *(const float4*)(qp + 16 * ks + 8 * hh);
    const float4 y = *(const float4*)(qp + 16 * ks + 8 * hh + 4);
    qf[ks] = (s8v){(short)f2b(x.x * QS), (short)f2b(x.y * QS),
                   (short)f2b(x.z * QS), (short)f2b(x.w * QS),
                   (short)f2b(y.x * QS), (short)f2b(y.y * QS),
                   (short)f2b(y.z * QS), (short)f2b(y.w * QS)};
  }

  // O^T accumulators: oacc[dblk][reg] = O[q=col][d=32dblk+(reg&3)+8(reg>>2)+4hh]
  f16vf oacc[4];
#pragma unroll
  for (int i = 0; i < 4; ++i)
#pragma unroll
    for (int j = 0; j < 16; ++j) oacc[i][j] = 0.f;
  float m_i = -1e30f, l_i = 0.f;

  // staging assignments
  const int kt = tid >> 2, kp4 = tid & 3;     // K: row kt, 32-col block kp4
  const int vtq = tid >> 4, vdq0 = tid & 15;  // V: 4 rows at 4*vtq, d-quads

  float4 kr[8], vr[8];  // prefetch registers (fp32)

  auto issue = [&](int kb) {
    const float* krp = Kb + ((size_t)(kb * 64 + kt)) * Dh + 32 * kp4;
#pragma unroll
    for (int gg = 0; gg < 4; ++gg) {
      kr[2 * gg] = *(const float4*)(krp + 8 * gg);
      kr[2 * gg + 1] = *(const float4*)(krp + 8 * gg + 4);
    }
#pragma unroll
    for (int u = 0; u < 2; ++u) {
      const int d0 = 4 * (vdq0 + 16 * u), t0 = 4 * vtq;
      const float* vrp = Vb + ((size_t)(kb * 64 + t0)) * Dh + d0;
#pragma unroll
      for (int r = 0; r < 4; ++r) vr[4 * u + r] = *(const float4*)(vrp + r * Dh);
    }
  };

  auto store_lds = [&]() {
#pragma unroll
    for (int gg = 0; gg < 4; ++gg) {
      const float* a = (const float*)&kr[2 * gg];
      const float* c = (const float*)&kr[2 * gg + 1];
      *(s8v*)&kl[kt * LDK + 32 * kp4 + 8 * gg] =
          (s8v){(short)f2b(a[0]), (short)f2b(a[1]), (short)f2b(a[2]),
                (short)f2b(a[3]), (short)f2b(c[0]), (short)f2b(c[1]),
                (short)f2b(c[2]), (short)f2b(c[3])};
    }
#pragma unroll
    for (int u = 0; u < 2; ++u) {
      const int d0 = 4 * (vdq0 + 16 * u), t0 = 4 * vtq;
      const float* f0 = (const float*)&vr[4 * u + 0];
      const float* f1 = (const float*)&vr[4 * u + 1];
      const float* f2 = (const float*)&vr[4 * u + 2];
      const float* f3 = (const float*)&vr[4 * u + 3];
#pragma unroll
      for (int c = 0; c < 4; ++c)
        *(s4v*)&vt[(d0 + c) * LDV + t0] =
            (s4v){(short)f2b(f0[c]), (short)f2b(f1[c]),
                  (short)f2b(f2[c]), (short)f2b(f3[c])};
    }
  };

  const int nkb = 2 * qt + 2;
  unsigned short* plw = pl + w * 32 * LDP;

  issue(0);
  store_lds();
  __syncthreads();

  for (int kb = 0; kb < nkb; ++kb) {
    const bool more = (kb + 1 < nkb);
    if (more) issue(kb + 1);  // prefetch next tile, overlapped with compute

    // ---- S^T = K * Q^T : sT[skb][reg] = S[q=col][key=32skb+(reg&3)+8(reg>>2)+4hh]
    f16vf sT[2];
#pragma unroll
    for (int skb = 0; skb < 2; ++skb) {
#pragma unroll
      for (int j = 0; j < 16; ++j) sT[skb][j] = 0.f;
#pragma unroll
      for (int ks = 0; ks < 8; ++ks) {
        s8v kf = *(const s8v*)&kl[(skb * 32 + col) * LDK + 16 * ks + 8 * hh];
        sT[skb] = __builtin_amdgcn_mfma_f32_32x32x16_bf16(kf, qf[ks], sT[skb], 0, 0, 0);
      }
    }

    // ---- causal mask (only last two key tiles can cross the diagonal)
    if (kb >= 2 * qt) {
#pragma unroll
      for (int skb = 0; skb < 2; ++skb)
#pragma unroll
        for (int j = 0; j < 16; ++j) {
          const int key = kb * 64 + skb * 32 + (j & 3) + 8 * (j >> 2) + 4 * hh;
          if (key > qrow) sT[skb][j] = -1e30f;
        }
    }

    // ---- online softmax: per-lane query (=col); single cross-lane hop (^32)
    float mx = sT[0][0];
#pragma unroll
    for (int j = 1; j < 16; ++j) mx = fmaxf(mx, sT[0][j]);
#pragma unroll
    for (int j = 0; j < 16; ++j) mx = fmaxf(mx, sT[1][j]);
    mx = fmaxf(mx, __shfl_xor(mx, 32));
    const float mn = fmaxf(m_i, mx);
    const float alpha = __builtin_amdgcn_exp2f(m_i - mn);
    m_i = mn;

    float ssum = 0.f;
#pragma unroll
    for (int skb = 0; skb < 2; ++skb) {
#pragma unroll
      for (int gg = 0; gg < 4; ++gg) {
        s4v pk;
#pragma unroll
        for (int r = 0; r < 4; ++r) {
          const float p = __builtin_amdgcn_exp2f(sT[skb][gg * 4 + r] - mn);
          const unsigned short pb = f2b(p);
          pk[r] = (short)pb;
          ssum += b2f(pb);  // denominator consistent with rounded numerator
        }
        *(s4v*)&plw[col * LDP + skb * 32 + 8 * gg + 4 * hh] = pk;
      }
    }
    ssum += __shfl_xor(ssum, 32);
    l_i = l_i * alpha + ssum;

    // ---- rescale O^T (alpha is per-lane: query = col)
#pragma unroll
    for (int i = 0; i < 4; ++i)
#pragma unroll
      for (int j = 0; j < 16; ++j) oacc[i][j] *= alpha;

    // ---- O^T += V^T * P^T
#pragma unroll
    for (int ksp = 0; ksp < 4; ++ksp) {
      s8v pf = *(const s8v*)&plw[col * LDP + 16 * ksp + 8 * hh];
#pragma unroll
      for (int dblk = 0; dblk < 4; ++dblk) {
        s8v vf = *(const s8v*)&vt[(dblk * 32 + col) * LDV + 16 * ksp + 8 * hh];
        oacc[dblk] = __builtin_amdgcn_mfma_f32_32x32x16_bf16(vf, pf, oacc[dblk], 0, 0, 0);
      }
    }

    if (more) {
      __syncthreads();  // all waves done reading kl/vt for kb
      store_lds();      // write prefetched kb+1
      __syncthreads();  // visible to all before next QK
    }
  }

  // ---- epilogue
  const float inv = 1.0f / l_i;
  float* op = Ob + (size_t)qrow * Dh;
#pragma unroll
  for (int dblk = 0; dblk < 4; ++dblk)
#pragma unroll
    for (int gg = 0; gg < 4; ++gg) {
      float4 st;
      st.x = oacc[dblk][4 * gg + 0] * inv;
      st.y = oacc[dblk][4 * gg + 1] * inv;
      st.z = oacc[dblk][4 * gg + 2] * inv;
      st.w = oacc[dblk][4 * gg + 3] * inv;
      *(float4*)(op + dblk * 32 + 8 * gg + 4 * hh) = st;
    }
}

extern "C" void kernel_launch(void* const* d_in, const int* in_sizes, int n_in,
                              void* d_out, int out_size, void* d_ws, size_t ws_size,
                              hipStream_t stream) {
  const float* q = (const float*)d_in[0];
  const float* k = (const float*)d_in[1];
  const float* v = (const float*)d_in[2];
  float* o = (float*)d_out;
  // 512 blocks: 32 (b,h) pairs x 16 q-tiles of 128 rows
  gqa_attn_kernel<<<dim3(512), dim3(256), 0, stream>>>(q, k, v, o);
}

// Round 3
// 158.699 us; speedup vs baseline: 2.3113x; 1.2570x over previous
//
#include <hip/hip_runtime.h>

typedef __attribute__((ext_vector_type(8))) short s8v;
typedef __attribute__((ext_vector_type(16))) float f16vf;

static __device__ __forceinline__ unsigned short f2b(float f) {
  unsigned int u = __builtin_bit_cast(unsigned int, f);
  u += 0x7fffu + ((u >> 16) & 1u);  // RNE
  return (unsigned short)(u >> 16);
}
static __device__ __forceinline__ float b2f(unsigned short b) {
  unsigned int u = ((unsigned int)b) << 16;
  return __builtin_bit_cast(float, u);
}

// async global->LDS DMA, 16B per lane; LDS dest must be wave-uniform base
static __device__ __forceinline__ void dma16(const void* g, void* l) {
  auto gp = reinterpret_cast<const __attribute__((address_space(1))) unsigned int*>(
      reinterpret_cast<uintptr_t>(g));
  auto lp = reinterpret_cast<__attribute__((address_space(3))) unsigned int*>(
      (unsigned int)reinterpret_cast<uintptr_t>(l));
  __builtin_amdgcn_global_load_lds(gp, lp, 16, 0, 0);
}

// ---------------- pre-pass: pack K and V^T as swizzled bf16 tiles ----------
// K tile (bk,kb): 64 rows(t) x 256B; 16B slot s stored at s ^ (t&15)
// V tile (bk,kb): 128 rows(d) x 128B (transposed); slot s at s ^ (d&7)
__global__ __launch_bounds__(256) void prepack_kernel(
    const float* __restrict__ K, const float* __restrict__ V,
    unsigned short* __restrict__ Kt, unsigned short* __restrict__ Vt) {
  __shared__ float vtile[64][129];
  const int bx = blockIdx.x;
  const int tile = bx & 511;  // bk*32 + kb
  const int bk = tile >> 5, kb = tile & 31;
  if (bx < 512) {
    const float* src = K + ((size_t)bk * 2048 + kb * 64) * 128;
    unsigned short* dst = Kt + (size_t)tile * 8192;
#pragma unroll
    for (int i = 0; i < 4; ++i) {
      const int task = threadIdx.x + 256 * i;  // 1024 = 64 rows x 16 slots
      const int row = task >> 4, slot = task & 15;
      const float* s = src + row * 128 + slot * 8;
      const float4 a = *(const float4*)s;
      const float4 b = *(const float4*)(s + 4);
      s8v o = (s8v){(short)f2b(a.x), (short)f2b(a.y), (short)f2b(a.z),
                    (short)f2b(a.w), (short)f2b(b.x), (short)f2b(b.y),
                    (short)f2b(b.z), (short)f2b(b.w)};
      *(s8v*)&dst[row * 128 + ((slot ^ (row & 15)) * 8)] = o;
    }
  } else {
    const float* src = V + ((size_t)bk * 2048 + kb * 64) * 128;
    unsigned short* dst = Vt + (size_t)tile * 8192;
#pragma unroll
    for (int i = 0; i < 8; ++i) {
      const int t4 = threadIdx.x + 256 * i;  // 2048 float4 loads
      const int row = t4 >> 5, c4 = t4 & 31;
      const float4 x = *(const float4*)(src + row * 128 + c4 * 4);
      vtile[row][c4 * 4 + 0] = x.x;
      vtile[row][c4 * 4 + 1] = x.y;
      vtile[row][c4 * 4 + 2] = x.z;
      vtile[row][c4 * 4 + 3] = x.w;
    }
    __syncthreads();
#pragma unroll
    for (int i = 0; i < 4; ++i) {
      const int task = threadIdx.x + 256 * i;  // 1024 = 128 d x 8 slots
      const int d = task >> 3, slot = task & 7;
      const int t0 = slot * 8;
      s8v o = (s8v){(short)f2b(vtile[t0 + 0][d]), (short)f2b(vtile[t0 + 1][d]),
                    (short)f2b(vtile[t0 + 2][d]), (short)f2b(vtile[t0 + 3][d]),
                    (short)f2b(vtile[t0 + 4][d]), (short)f2b(vtile[t0 + 5][d]),
                    (short)f2b(vtile[t0 + 6][d]), (short)f2b(vtile[t0 + 7][d])};
      *(s8v*)&dst[d * 64 + ((slot ^ (d & 7)) * 8)] = o;
    }
  }
}

// ---------------- attention kernel ----------------
__global__ __launch_bounds__(256, 2) void gqa_attn_kernel(
    const float* __restrict__ Q, const unsigned short* __restrict__ Kt,
    const unsigned short* __restrict__ Vt, float* __restrict__ O) {
  constexpr int S = 2048, Dh = 128;
  constexpr float QS = 0.08838834764831845f * 1.4426950408889634f;  // 1/sqrt(128)*log2e

  __shared__ unsigned short kl[2][8192];  // 2 x 16KB K tiles (swizzled)
  __shared__ unsigned short vt[2][8192];  // 2 x 16KB V^T tiles (swizzled)

  const int tid = threadIdx.x;
  const int l = tid & 63, w = tid >> 6;
  const int col = l & 31, hh = l >> 5;
  const bool h1 = hh != 0;

  const int bx = blockIdx.x;
  const int bh = bx & 31;  // b*16 + h
  const int g = bx >> 5;
  const int qt = (g < 8) ? (15 - g) : (g - 8);  // zigzag pairing, heavy first
  const int b = bh >> 4, h = bh & 15;
  const int bk = b * 8 + (h >> 1);

  const float* Qb = Q + ((size_t)bh * S) * Dh;
  const unsigned short* Ktb = Kt + (size_t)bk * 32 * 8192;
  const unsigned short* Vtb = Vt + (size_t)bk * 32 * 8192;
  float* Ob = O + ((size_t)bh * S) * Dh;

  // Q fragments (B-operand): lane holds Q[q=col][d=16ks+8hh+j], pre-scaled
  const int qrow = qt * 128 + w * 32 + col;
  const float* qp = Qb + (size_t)qrow * Dh;
  s8v qf[8];
#pragma unroll
  for (int ks = 0; ks < 8; ++ks) {
    const float4 x = *(const float4*)(qp + 16 * ks + 8 * hh);
    const float4 y = *(const float4*)(qp + 16 * ks + 8 * hh + 4);
    qf[ks] = (s8v){(short)f2b(x.x * QS), (short)f2b(x.y * QS),
                   (short)f2b(x.z * QS), (short)f2b(x.w * QS),
                   (short)f2b(y.x * QS), (short)f2b(y.y * QS),
                   (short)f2b(y.z * QS), (short)f2b(y.w * QS)};
  }

  f16vf oacc[4];  // O^T: oacc[dblk][r] = O[q=col][d=32dblk+(r&3)+8(r>>2)+4hh]
#pragma unroll
  for (int i = 0; i < 4; ++i)
#pragma unroll
    for (int j = 0; j < 16; ++j) oacc[i][j] = 0.f;
  float m_i = -1e30f, l_i = 0.f;

  auto stage = [&](int kb, int pbuf) {
    const unsigned short* kg = Ktb + (size_t)kb * 8192;
    const unsigned short* vg = Vtb + (size_t)kb * 8192;
#pragma unroll
    for (int c = 0; c < 4; ++c) {
      const int chunk = 4 * w + c;  // 16 x 1KB chunks per tile
      dma16(kg + chunk * 512 + l * 8, &kl[pbuf][chunk * 512]);
      dma16(vg + chunk * 512 + l * 8, &vt[pbuf][chunk * 512]);
    }
  };

  const int nkb = 2 * qt + 2;
  stage(0, 0);
  __syncthreads();  // drains vmcnt(0): DMA landed

  for (int kb = 0; kb < nkb; ++kb) {
    const int pb = kb & 1;
    const bool more = (kb + 1 < nkb);
    if (more) stage(kb + 1, pb ^ 1);  // DMA in flight during compute

    // ---- S^T = K * Q^T: sT[skb][r] = S[q=col][key=32skb+(r&3)+8(r>>2)+4hh]
    f16vf sT[2];
#pragma unroll
    for (int skb = 0; skb < 2; ++skb) {
#pragma unroll
      for (int j = 0; j < 16; ++j) sT[skb][j] = 0.f;
#pragma unroll
      for (int ks = 0; ks < 8; ++ks) {
        const int t = skb * 32 + col;
        s8v kf = *(const s8v*)&kl[pb][t * 128 + (((2 * ks + hh) ^ (col & 15)) * 8)];
        sT[skb] = __builtin_amdgcn_mfma_f32_32x32x16_bf16(kf, qf[ks], sT[skb], 0, 0, 0);
      }
    }

    // ---- causal mask (last two key tiles only)
    if (kb >= 2 * qt) {
#pragma unroll
      for (int skb = 0; skb < 2; ++skb)
#pragma unroll
        for (int j = 0; j < 16; ++j) {
          const int key = kb * 64 + skb * 32 + (j & 3) + 8 * (j >> 2) + 4 * hh;
          if (key > qrow) sT[skb][j] = -1e30f;
        }
    }

    // ---- online softmax (query = lane col; one cross-lane hop)
    float mx = sT[0][0];
#pragma unroll
    for (int j = 1; j < 16; ++j) mx = fmaxf(mx, sT[0][j]);
#pragma unroll
    for (int j = 0; j < 16; ++j) mx = fmaxf(mx, sT[1][j]);
    mx = fmaxf(mx, __shfl_xor(mx, 32));
    const float mn = fmaxf(m_i, mx);
    const float alpha = __builtin_amdgcn_exp2f(m_i - mn);
    m_i = mn;

    unsigned int pdw[2][8];
    float ssum = 0.f;
#pragma unroll
    for (int skb = 0; skb < 2; ++skb)
#pragma unroll
      for (int q = 0; q < 8; ++q) {
        const float p0 = __builtin_amdgcn_exp2f(sT[skb][2 * q] - mn);
        const float p1 = __builtin_amdgcn_exp2f(sT[skb][2 * q + 1] - mn);
        const unsigned short b0 = f2b(p0), b1 = f2b(p1);
        ssum += b2f(b0) + b2f(b1);  // denominator from rounded numerator
        pdw[skb][q] = (unsigned int)b0 | ((unsigned int)b1 << 16);
      }
    ssum += __shfl_xor(ssum, 32);
    l_i = l_i * alpha + ssum;

    // ---- rescale O^T
#pragma unroll
    for (int i = 0; i < 4; ++i)
#pragma unroll
      for (int j = 0; j < 16; ++j) oacc[i][j] *= alpha;

    // ---- PV: build P^T B-fragments via half-wave exchange; O^T += V^T P^T
#pragma unroll
    for (int ksp = 0; ksp < 4; ++ksp) {
      const int sk = ksp >> 1, e4 = (ksp & 1) * 4;
      // own dwords hold keys for this lane's hh; partner's same indices hold
      // the other half-slice (derivation: key=16ksp+8hh+4jh+b, src reg 4g0+b,
      // g0=2(ksp&1)+hh, src lane hh'=jh)
      const unsigned int own0 = h1 ? pdw[sk][e4 + 2] : pdw[sk][e4 + 0];
      const unsigned int own1 = h1 ? pdw[sk][e4 + 3] : pdw[sk][e4 + 1];
      const unsigned int snd0 = h1 ? pdw[sk][e4 + 0] : pdw[sk][e4 + 2];
      const unsigned int snd1 = h1 ? pdw[sk][e4 + 1] : pdw[sk][e4 + 3];
      const unsigned int rcv0 = (unsigned int)__shfl_xor((int)snd0, 32);
      const unsigned int rcv1 = (unsigned int)__shfl_xor((int)snd1, 32);
      unsigned int pw[4];
      pw[0] = h1 ? rcv0 : own0;  // j=0..1 (hh'=0 source)
      pw[1] = h1 ? rcv1 : own1;  // j=2..3
      pw[2] = h1 ? own0 : rcv0;  // j=4..5 (hh'=1 source)
      pw[3] = h1 ? own1 : rcv1;  // j=6..7
      s8v pf = __builtin_bit_cast(s8v, *(const __attribute__((ext_vector_type(4))) unsigned int*)pw);
#pragma unroll
      for (int dblk = 0; dblk < 4; ++dblk) {
        const int d = dblk * 32 + col;
        s8v vf = *(const s8v*)&vt[pb][d * 64 + (((2 * ksp + hh) ^ (col & 7)) * 8)];
        oacc[dblk] = __builtin_amdgcn_mfma_f32_32x32x16_bf16(vf, pf, oacc[dblk], 0, 0, 0);
      }
    }

    if (more) __syncthreads();  // drain DMA(kb+1) + guard buffer reuse
  }

  // ---- epilogue
  const float inv = 1.0f / l_i;
  float* op = Ob + (size_t)qrow * Dh;
#pragma unroll
  for (int dblk = 0; dblk < 4; ++dblk)
#pragma unroll
    for (int gg = 0; gg < 4; ++gg) {
      float4 st;
      st.x = oacc[dblk][4 * gg + 0] * inv;
      st.y = oacc[dblk][4 * gg + 1] * inv;
      st.z = oacc[dblk][4 * gg + 2] * inv;
      st.w = oacc[dblk][4 * gg + 3] * inv;
      *(float4*)(op + dblk * 32 + 8 * gg + 4 * hh) = st;
    }
}

extern "C" void kernel_launch(void* const* d_in, const int* in_sizes, int n_in,
                              void* d_out, int out_size, void* d_ws, size_t ws_size,
                              hipStream_t stream) {
  const float* q = (const float*)d_in[0];
  const float* k = (const float*)d_in[1];
  const float* v = (const float*)d_in[2];
  float* o = (float*)d_out;
  unsigned short* Kt = (unsigned short*)d_ws;           // 16 heads x 32 tiles x 16KB = 8MB
  unsigned short* Vt = Kt + (size_t)16 * 32 * 8192;     // +8MB
  prepack_kernel<<<dim3(1024), dim3(256), 0, stream>>>(k, v, Kt, Vt);
  gqa_attn_kernel<<<dim3(512), dim3(256), 0, stream>>>(q, Kt, Vt, o);
}

// Round 4
// 158.498 us; speedup vs baseline: 2.3142x; 1.0013x over previous
//
#include <hip/hip_runtime.h>

typedef __attribute__((ext_vector_type(8))) short s8v;
typedef __attribute__((ext_vector_type(16))) float f16vf;
typedef __attribute__((ext_vector_type(4))) unsigned int u4v;
typedef __attribute__((ext_vector_type(2))) unsigned int u2v;

static __device__ __forceinline__ unsigned short f2b(float f) {
  unsigned int u = __builtin_bit_cast(unsigned int, f);
  u += 0x7fffu + ((u >> 16) & 1u);  // RNE
  return (unsigned short)(u >> 16);
}

#if defined(__has_builtin)
#if __has_builtin(__builtin_amdgcn_cvt_pk_bf16_f32)
#define HAVE_PK_BF16 1
#endif
#endif

// pack two floats -> bf16x2 dword (lo = a, hi = b), RNE
static __device__ __forceinline__ unsigned int pk2(float a, float b) {
#ifdef HAVE_PK_BF16
  auto r = __builtin_amdgcn_cvt_pk_bf16_f32(a, b);
  static_assert(sizeof(r) == 4, "pk bf16 size");
  return __builtin_bit_cast(unsigned int, r);
#else
  return (unsigned int)f2b(a) | ((unsigned int)f2b(b) << 16);
#endif
}

// async global->LDS DMA, 16B/lane; LDS dest wave-uniform base + lane*16
static __device__ __forceinline__ void dma16(const void* g, void* l) {
  auto gp = reinterpret_cast<const __attribute__((address_space(1))) unsigned int*>(
      reinterpret_cast<uintptr_t>(g));
  auto lp = reinterpret_cast<__attribute__((address_space(3))) unsigned int*>(
      (unsigned int)reinterpret_cast<uintptr_t>(l));
  __builtin_amdgcn_global_load_lds(gp, lp, 16, 0, 0);
}

// ---------------- pre-pass: pack K and V^T as swizzled bf16 tiles ----------
// K tile: 64 rows(t) x 128 bf16; 16B slot s of row t stored at s ^ (t&15)
// V tile: 128 rows(d) x 64 bf16 (transposed); slot s of row d at s ^ (d&7)
__global__ __launch_bounds__(256) void prepack_kernel(
    const float* __restrict__ K, const float* __restrict__ V,
    unsigned short* __restrict__ Kt, unsigned short* __restrict__ Vt) {
  const int bx = blockIdx.x;
  const int tile = bx & 511;  // bk*32 + kb
  const int bk = tile >> 5, kb = tile & 31;
  const int tid = threadIdx.x;
  if (bx < 512) {
    const float* src = K + ((size_t)bk * 2048 + kb * 64) * 128;
    unsigned short* dst = Kt + (size_t)tile * 8192;
#pragma unroll
    for (int i = 0; i < 4; ++i) {
      const int task = tid + 256 * i;  // 1024 = 64 rows x 16 slots
      const int row = task >> 4, slot = task & 15;
      const float* s = src + row * 128 + slot * 8;
      const float4 a = *(const float4*)s;
      const float4 b = *(const float4*)(s + 4);
      u4v o = (u4v){pk2(a.x, a.y), pk2(a.z, a.w), pk2(b.x, b.y), pk2(b.z, b.w)};
      *(u4v*)&dst[row * 128 + ((slot ^ (row & 15)) * 8)] = o;
    }
  } else {
    // V: 4x4 register-block transpose, no LDS
    const float* src = V + ((size_t)bk * 2048 + kb * 64) * 128;
    unsigned short* dst = Vt + (size_t)tile * 8192;
    const int vtq = tid >> 4, vdq0 = tid & 15;  // t-quad, d-quad base
#pragma unroll
    for (int u = 0; u < 2; ++u) {
      const int d0 = 4 * (vdq0 + 16 * u), t0 = 4 * vtq;
      const float* vr = src + (size_t)t0 * 128 + d0;
      const float4 r0 = *(const float4*)(vr);
      const float4 r1 = *(const float4*)(vr + 128);
      const float4 r2 = *(const float4*)(vr + 256);
      const float4 r3 = *(const float4*)(vr + 384);
      const float* f0 = (const float*)&r0;
      const float* f1 = (const float*)&r1;
      const float* f2 = (const float*)&r2;
      const float* f3 = (const float*)&r3;
#pragma unroll
      for (int c = 0; c < 4; ++c) {
        const int d = d0 + c;
        const int eoff = d * 64 + (((vtq >> 1) ^ (d & 7)) << 3) + (t0 & 7);
        *(u2v*)&dst[eoff] = (u2v){pk2(f0[c], f1[c]), pk2(f2[c], f3[c])};
      }
    }
  }
}

// ---------------- attention kernel ----------------
__global__ __launch_bounds__(256, 2) void gqa_attn_kernel(
    const float* __restrict__ Q, const unsigned short* __restrict__ Kt,
    const unsigned short* __restrict__ Vt, float* __restrict__ O) {
  constexpr int S = 2048, Dh = 128;
  constexpr float QS = 0.08838834764831845f * 1.4426950408889634f;  // 1/sqrt(128)*log2e

  __shared__ unsigned short kl[2 * 8192];  // 2 x 16KB K tiles (swizzled)
  __shared__ unsigned short vt[2 * 8192];  // 2 x 16KB V^T tiles (swizzled)

  const int tid = threadIdx.x;
  const int l = tid & 63, w = tid >> 6;
  const int col = l & 31, hh = l >> 5;
  const bool h1 = hh != 0;

  const int bx = blockIdx.x;
  const int bh = bx & 31;  // b*16 + h
  const int g = bx >> 5;
  const int qt = (g < 8) ? (15 - g) : (g - 8);  // zigzag pairing, heavy first
  const int b = bh >> 4, h = bh & 15;
  const int bk = b * 8 + (h >> 1);

  const float* Qb = Q + ((size_t)bh * S) * Dh;
  const unsigned short* Ktb = Kt + (size_t)bk * 32 * 8192;
  const unsigned short* Vtb = Vt + (size_t)bk * 32 * 8192;
  float* Ob = O + ((size_t)bh * S) * Dh;

  const char* klc = (const char*)kl;
  const char* vtc = (const char*)vt;

  auto stage = [&](int kb, int bo) {
    const unsigned short* kg = Ktb + (size_t)kb * 8192;
    const unsigned short* vg = Vtb + (size_t)kb * 8192;
    char* klp = (char*)kl + bo;
    char* vlp = (char*)vt + bo;
#pragma unroll
    for (int c = 0; c < 4; ++c) {
      const int chunk = 4 * w + c;  // 16 x 1KB chunks per tile
      dma16(kg + chunk * 512 + l * 8, klp + chunk * 1024);
      dma16(vg + chunk * 512 + l * 8, vlp + chunk * 1024);
    }
  };

  const int nkb = 2 * qt + 2;  // always even
  stage(0, 0);  // DMA in flight during Q-fragment conversion

  // Q fragments (B-operand): lane holds Q[q=col][d=16ks+8hh+j], pre-scaled
  const int qrow = qt * 128 + w * 32 + col;
  const float* qp = Qb + (size_t)qrow * Dh;
  s8v qf[8];
#pragma unroll
  for (int ks = 0; ks < 8; ++ks) {
    const float4 x = *(const float4*)(qp + 16 * ks + 8 * hh);
    const float4 y = *(const float4*)(qp + 16 * ks + 8 * hh + 4);
    u4v q4 = (u4v){pk2(x.x * QS, x.y * QS), pk2(x.z * QS, x.w * QS),
                   pk2(y.x * QS, y.y * QS), pk2(y.z * QS, y.w * QS)};
    qf[ks] = __builtin_bit_cast(s8v, q4);
  }

  // hoisted LDS byte offsets (loop-invariant; buffer half goes in the
  // ds_read immediate via the unroll-by-2 below)
  int koff[16], voff[16];
#pragma unroll
  for (int skb = 0; skb < 2; ++skb)
#pragma unroll
    for (int ks = 0; ks < 8; ++ks)
      koff[skb * 8 + ks] =
          ((skb * 32 + col) * 128 + (((2 * ks + hh) ^ (col & 15)) * 8)) * 2;
#pragma unroll
  for (int dblk = 0; dblk < 4; ++dblk)
#pragma unroll
    for (int ksp = 0; ksp < 4; ++ksp)
      voff[dblk * 4 + ksp] =
          ((dblk * 32 + col) * 64 + (((2 * ksp + hh) ^ (col & 7)) * 8)) * 2;

  f16vf oacc[4];  // O^T: oacc[dblk][r] = O[q=col][d=32dblk+(r&3)+8(r>>2)+4hh]
#pragma unroll
  for (int i = 0; i < 4; ++i)
#pragma unroll
    for (int j = 0; j < 16; ++j) oacc[i][j] = 0.f;
  float m_i = -1e30f, l_i = 0.f;

  __syncthreads();  // drains vmcnt(0): first DMA landed

  auto body = [&](int kb, int bo) {
    const bool more = (kb + 1 < nkb);
    if (more) stage(kb + 1, bo ^ 16384);  // DMA in flight during compute

    // ---- S^T = K * Q^T: sT[skb][r] = S[q=col][key=32skb+(r&3)+8(r>>2)+4hh]
    f16vf sT[2];
#pragma unroll
    for (int skb = 0; skb < 2; ++skb) {
#pragma unroll
      for (int j = 0; j < 16; ++j) sT[skb][j] = 0.f;
#pragma unroll
      for (int ks = 0; ks < 8; ++ks) {
        s8v kf = *(const s8v*)(klc + koff[skb * 8 + ks] + bo);
        sT[skb] = __builtin_amdgcn_mfma_f32_32x32x16_bf16(kf, qf[ks], sT[skb], 0, 0, 0);
      }
    }

    // ---- causal mask (last two key tiles only)
    if (kb >= 2 * qt) {
#pragma unroll
      for (int skb = 0; skb < 2; ++skb)
#pragma unroll
        for (int j = 0; j < 16; ++j) {
          const int key = kb * 64 + skb * 32 + (j & 3) + 8 * (j >> 2) + 4 * hh;
          if (key > qrow) sT[skb][j] = -1e30f;
        }
    }

    // ---- online softmax (query = lane col); tree reductions
    float t16[16];
#pragma unroll
    for (int j = 0; j < 16; ++j) t16[j] = fmaxf(sT[0][j], sT[1][j]);
#pragma unroll
    for (int j = 0; j < 8; ++j) t16[j] = fmaxf(t16[j], t16[j + 8]);
#pragma unroll
    for (int j = 0; j < 4; ++j) t16[j] = fmaxf(t16[j], t16[j + 4]);
    float mx = fmaxf(fmaxf(t16[0], t16[1]), fmaxf(t16[2], t16[3]));
    mx = fmaxf(mx, __shfl_xor(mx, 32));
    const float mn = fmaxf(m_i, mx);
    const float alpha = __builtin_amdgcn_exp2f(m_i - mn);
    m_i = mn;

    unsigned int pdw[2][8];
    float ps[4] = {0.f, 0.f, 0.f, 0.f};
#pragma unroll
    for (int skb = 0; skb < 2; ++skb)
#pragma unroll
      for (int q = 0; q < 8; ++q) {
        const float p0 = __builtin_amdgcn_exp2f(sT[skb][2 * q] - mn);
        const float p1 = __builtin_amdgcn_exp2f(sT[skb][2 * q + 1] - mn);
        pdw[skb][q] = pk2(p0, p1);
        ps[q & 3] += p0 + p1;  // denominator from unrounded p (4 chains)
      }
    float ssum = (ps[0] + ps[1]) + (ps[2] + ps[3]);
    ssum += __shfl_xor(ssum, 32);
    l_i = l_i * alpha + ssum;

    // ---- rescale O^T
#pragma unroll
    for (int i = 0; i < 4; ++i)
#pragma unroll
      for (int j = 0; j < 16; ++j) oacc[i][j] *= alpha;

    // ---- PV: P^T B-fragments via half-wave exchange; O^T += V^T P^T
#pragma unroll
    for (int ksp = 0; ksp < 4; ++ksp) {
      const int sk = ksp >> 1, e4 = (ksp & 1) * 4;
      const unsigned int own0 = h1 ? pdw[sk][e4 + 2] : pdw[sk][e4 + 0];
      const unsigned int own1 = h1 ? pdw[sk][e4 + 3] : pdw[sk][e4 + 1];
      const unsigned int snd0 = h1 ? pdw[sk][e4 + 0] : pdw[sk][e4 + 2];
      const unsigned int snd1 = h1 ? pdw[sk][e4 + 1] : pdw[sk][e4 + 3];
      const unsigned int rcv0 = (unsigned int)__shfl_xor((int)snd0, 32);
      const unsigned int rcv1 = (unsigned int)__shfl_xor((int)snd1, 32);
      u4v pw;
      pw[0] = h1 ? rcv0 : own0;
      pw[1] = h1 ? rcv1 : own1;
      pw[2] = h1 ? own0 : rcv0;
      pw[3] = h1 ? own1 : rcv1;
      s8v pf = __builtin_bit_cast(s8v, pw);
#pragma unroll
      for (int dblk = 0; dblk < 4; ++dblk) {
        s8v vf = *(const s8v*)(vtc + voff[dblk * 4 + ksp] + bo);
        oacc[dblk] = __builtin_amdgcn_mfma_f32_32x32x16_bf16(vf, pf, oacc[dblk], 0, 0, 0);
      }
    }

    if (more) __syncthreads();  // drain DMA(kb+1) + guard buffer reuse
  };

  for (int kb = 0; kb < nkb; kb += 2) {
    body(kb, 0);
    body(kb + 1, 16384);
  }

  // ---- epilogue
  const float inv = 1.0f / l_i;
  float* op = Ob + (size_t)qrow * Dh;
#pragma unroll
  for (int dblk = 0; dblk < 4; ++dblk)
#pragma unroll
    for (int gg = 0; gg < 4; ++gg) {
      float4 st;
      st.x = oacc[dblk][4 * gg + 0] * inv;
      st.y = oacc[dblk][4 * gg + 1] * inv;
      st.z = oacc[dblk][4 * gg + 2] * inv;
      st.w = oacc[dblk][4 * gg + 3] * inv;
      *(float4*)(op + dblk * 32 + 8 * gg + 4 * hh) = st;
    }
}

extern "C" void kernel_launch(void* const* d_in, const int* in_sizes, int n_in,
                              void* d_out, int out_size, void* d_ws, size_t ws_size,
                              hipStream_t stream) {
  const float* q = (const float*)d_in[0];
  const float* k = (const float*)d_in[1];
  const float* v = (const float*)d_in[2];
  float* o = (float*)d_out;
  unsigned short* Kt = (unsigned short*)d_ws;        // 16 bk x 32 tiles x 16KB = 8MB
  unsigned short* Vt = Kt + (size_t)16 * 32 * 8192;  // +8MB
  prepack_kernel<<<dim3(1024), dim3(256), 0, stream>>>(k, v, Kt, Vt);
  gqa_attn_kernel<<<dim3(512), dim3(256), 0, stream>>>(q, Kt, Vt, o);
}